// Round 1
// baseline (397.624 us; speedup 1.0000x reference)
//
#include <hip/hip_runtime.h>
#include <math.h>

#define B_   16
#define N_   16384
#define H_   8192      // N/2
#define LOGH 13
#define CIN  64
#define COUT 64
#define T_   256
#define M_   2049

__device__ __forceinline__ unsigned br13(unsigned v) {
  return __brev(v) >> 19;   // 13-bit reversal
}

// ---------------- Kernel A: t_mod = t_emb @ dense^T (complex) ----------------
__global__ __launch_bounds__(256) void tmod_kernel(
    const float* __restrict__ t_emb,
    const float* __restrict__ dwr, const float* __restrict__ dwi,
    float* __restrict__ tmr, float* __restrict__ tmi) {
  int wave = threadIdx.x >> 6;   // 0..3
  int lane = threadIdx.x & 63;
  int p = blockIdx.x * 4 + wave; // pair index over (b,i)
  if (p >= B_ * M_) return;
  int b = p / M_, i = p % M_;
  float ar = 0.f, ai = 0.f;
  for (int j = 0; j < 4; ++j) {
    int t = lane + 64 * j;
    float te = t_emb[b * T_ + t];
    ar += te * dwr[(size_t)i * T_ + t];
    ai += te * dwi[(size_t)i * T_ + t];
  }
  for (int off = 32; off > 0; off >>= 1) {
    ar += __shfl_down(ar, off, 64);
    ai += __shfl_down(ai, off, 64);
  }
  if (lane == 0) { tmr[b * M_ + i] = ar; tmi[b * M_ + i] = ai; }
}

// ------- Kernel T1: x (B,N,C) -> packed complex planes z (B*C, H) ------------
// zre[b,c,n] = x[b,2n,c], zim[b,c,n] = x[b,2n+1,c]
__global__ __launch_bounds__(256) void pack_transpose(
    const float* __restrict__ x, float* __restrict__ zre, float* __restrict__ zim) {
  __shared__ float tile[64][65];
  int b = blockIdx.y, nt = blockIdx.x;
  int n0 = nt * 64;
  int j  = threadIdx.x & 63;   // c
  int iy = threadIdx.x >> 6;   // 0..3
  for (int p = 0; p < 16; ++p) {
    int i = iy + 4 * p;
    tile[i][j] = x[((size_t)(b * N_ + n0 + i)) * CIN + j];
  }
  __syncthreads();
  int ii = threadIdx.x & 31;
  int cy = threadIdx.x >> 5;   // 0..7
  int h0 = nt * 32;
  for (int p = 0; p < 8; ++p) {
    int c = cy + 8 * p;
    size_t o = (size_t)(b * CIN + c) * H_ + h0 + ii;
    zre[o] = tile[2 * ii][c];
    zim[o] = tile[2 * ii + 1][c];
  }
}

// ---------------- Kernel B: forward FFT (length H) + rfft split --------------
// one block per (b,c); writes X (b,c,k) for k<M, scaled 1/N
__global__ __launch_bounds__(512) void fft_fwd(
    const float* __restrict__ zre, const float* __restrict__ zim,
    float* __restrict__ Xre, float* __restrict__ Xim) {
  __shared__ float sre[H_], sim[H_];
  int bc = blockIdx.x;
  int tid = threadIdx.x;
  size_t base = (size_t)bc * H_;
  for (int s = 0; s < H_ / 512; ++s) {
    int n = tid + 512 * s;
    unsigned r = br13(n);
    sre[r] = zre[base + n];
    sim[r] = zim[base + n];
  }
  __syncthreads();
  for (int lh = 0; lh < LOGH; ++lh) {
    int half = 1 << lh;
    float w0 = -6.283185307179586f / (float)(2 << lh);
    for (int t = 0; t < 8; ++t) {
      int jj = tid + 512 * t;             // 0..4095
      int k  = jj & (half - 1);
      int i0 = ((jj >> lh) << (lh + 1)) + k;
      int i1 = i0 + half;
      float ang = w0 * (float)k;
      float wi, wr;
      __sincosf(ang, &wi, &wr);           // wi=sin, wr=cos
      float xr = sre[i1], xi = sim[i1];
      float br_ = xr * wr - xi * wi;
      float bi_ = xr * wi + xi * wr;
      float ar = sre[i0], ai = sim[i0];
      sre[i0] = ar + br_; sim[i0] = ai + bi_;
      sre[i1] = ar - br_; sim[i1] = ai - bi_;
    }
    __syncthreads();
  }
  // rfft split: X_k = E + e^{-2pi i k/N} O, then * 1/N
  const float sc = 1.0f / (float)N_;
  for (int k = tid; k < M_; k += 512) {
    int mk = (H_ - k) & (H_ - 1);
    float zr = sre[k],  zi = sim[k];
    float mr = sre[mk], mi = -sim[mk];    // conj(Z[H-k])
    float Er = 0.5f * (zr + mr), Ei = 0.5f * (zi + mi);
    float Dr = zr - mr,          Di = zi - mi;
    float Or = 0.5f * Di,        Oi = -0.5f * Dr;  // D/(2i)
    float ang = -6.283185307179586f * (float)k / (float)N_;
    float sn, cs;
    __sincosf(ang, &sn, &cs);
    float Xr = Er + cs * Or - sn * Oi;
    float Xi = Ei + cs * Oi + sn * Or;
    Xre[(size_t)bc * M_ + k] = Xr * sc;
    Xim[(size_t)bc * M_ + k] = Xi * sc;
  }
}

// ---------------- generic 2-plane tiled transpose (R x C -> C x R) ----------
__global__ __launch_bounds__(256) void transpose2(
    const float* __restrict__ s0, const float* __restrict__ s1,
    float* __restrict__ d0, float* __restrict__ d1, int R, int C) {
  __shared__ float tile[32][33];
  const float* src = blockIdx.z ? s1 : s0;
  float* dst = blockIdx.z ? d1 : d0;
  int c0 = blockIdx.x * 32, r0 = blockIdx.y * 32;
  int tx = threadIdx.x & 31, ty = threadIdx.x >> 5; // ty 0..7
  for (int p = 0; p < 32; p += 8) {
    int r = r0 + ty + p, c = c0 + tx;
    tile[ty + p][tx] = (r < R && c < C) ? src[(size_t)r * C + c] : 0.f;
  }
  __syncthreads();
  for (int p = 0; p < 32; p += 8) {
    int r = c0 + ty + p, c = r0 + tx;
    if (r < C && c < R) dst[(size_t)r * R + c] = tile[tx][ty + p];
  }
}

// ---------------- Kernel C: per-frequency channel mix ------------------------
// Y[i,b,o] = tmod[b,i] * sum_c X[i,b,c]*W[i,c,o]   (complex, in-place over Xt)
__global__ __launch_bounds__(256) void mix_kernel(
    const float* __restrict__ Xtr, const float* __restrict__ Xti,
    const float* __restrict__ Wr_g, const float* __restrict__ Wi_g,
    const float* __restrict__ tmr, const float* __restrict__ tmi,
    float* __restrict__ Yr_g, float* __restrict__ Yi_g) {
  __shared__ float Wr[4096], Wi[4096], Xr[1024], Xi[1024];
  int i = blockIdx.x;
  int tid = threadIdx.x;
  for (int idx = tid; idx < 4096; idx += 256) {
    Wr[idx] = Wr_g[(size_t)i * 4096 + idx];
    Wi[idx] = Wi_g[(size_t)i * 4096 + idx];
  }
  for (int idx = tid; idx < 1024; idx += 256) {
    Xr[idx] = Xtr[(size_t)i * 1024 + idx];
    Xi[idx] = Xti[(size_t)i * 1024 + idx];
  }
  __syncthreads();
  int o = tid & 63, bq = tid >> 6;
  for (int bb = 0; bb < 4; ++bb) {
    int b = bq + 4 * bb;
    float ar = 0.f, ai = 0.f;
    for (int c = 0; c < 64; ++c) {
      float xr = Xr[b * 64 + c], xi = Xi[b * 64 + c];
      float wr = Wr[c * 64 + o], wi = Wi[c * 64 + o];
      ar += xr * wr - xi * wi;
      ai += xr * wi + xi * wr;
    }
    float tr = tmr[b * M_ + i], ti = tmi[b * M_ + i];
    float yr = tr * ar - ti * ai;
    float yi = tr * ai + ti * ar;
    size_t oidx = ((size_t)i * 16 + b) * 64 + o;
    Yr_g[oidx] = yr;
    Yi_g[oidx] = yi;
  }
}

// ---------------- Kernel D: inverse packing + inverse FFT --------------------
// one block per (b,o); reads Yt (b*64+o, k) k<M; writes z planes (b*64+o, n)
__global__ __launch_bounds__(512) void fft_inv(
    const float* __restrict__ Ytr, const float* __restrict__ Yti,
    float* __restrict__ zre, float* __restrict__ zim) {
  __shared__ float sre[H_], sim[H_];
  int bo = blockIdx.x;
  int tid = threadIdx.x;
  size_t ybase = (size_t)bo * M_;
  for (int s = 0; s < H_ / 512; ++s) {
    int k = tid + 512 * s;
    float ykr = 0.f, yki = 0.f, ymr = 0.f, ymi = 0.f;
    if (k < M_) { ykr = Ytr[ybase + k]; yki = Yti[ybase + k]; }
    int m = H_ - k;                    // 1..8192 — NO wraparound (Y_H = 0)
    if (m < M_) { ymr = Ytr[ybase + m]; ymi = -Yti[ybase + m]; } // conj
    float Sr = ykr + ymr, Si = yki + ymi;
    float Dr = ykr - ymr, Di = yki - ymi;
    float ang = 6.283185307179586f * (float)k / (float)N_;
    float sn, cs;
    __sincosf(ang, &sn, &cs);
    // Z = S + i*tw*D, tw = (cs, sn)
    float Zr = Sr - (cs * Di + sn * Dr);
    float Zi = Si + (cs * Dr - sn * Di);
    unsigned r = br13(k);
    sre[r] = Zr; sim[r] = Zi;
  }
  __syncthreads();
  for (int lh = 0; lh < LOGH; ++lh) {
    int half = 1 << lh;
    float w0 = 6.283185307179586f / (float)(2 << lh);  // + sign (inverse)
    for (int t = 0; t < 8; ++t) {
      int jj = tid + 512 * t;
      int k  = jj & (half - 1);
      int i0 = ((jj >> lh) << (lh + 1)) + k;
      int i1 = i0 + half;
      float ang = w0 * (float)k;
      float wi, wr;
      __sincosf(ang, &wi, &wr);
      float xr = sre[i1], xi = sim[i1];
      float br_ = xr * wr - xi * wi;
      float bi_ = xr * wi + xi * wr;
      float ar = sre[i0], ai = sim[i0];
      sre[i0] = ar + br_; sim[i0] = ai + bi_;
      sre[i1] = ar - br_; sim[i1] = ai - bi_;
    }
    __syncthreads();
  }
  size_t base = (size_t)bo * H_;
  for (int s = 0; s < H_ / 512; ++s) {
    int n = tid + 512 * s;
    zre[base + n] = sre[n];
    zim[base + n] = sim[n];
  }
}

// ------- Kernel T4: z planes (B*Cout, H) -> out (B, N, Cout) -----------------
__global__ __launch_bounds__(256) void unpack_transpose(
    const float* __restrict__ zre, const float* __restrict__ zim,
    float* __restrict__ out) {
  __shared__ float tre[64][33], tim[64][33];
  int b = blockIdx.y, ht = blockIdx.x;
  int h0 = ht * 32;
  int ii = threadIdx.x & 31, cy = threadIdx.x >> 5; // cy 0..7
  for (int p = 0; p < 8; ++p) {
    int c = cy + 8 * p;
    size_t idx = (size_t)(b * COUT + c) * H_ + h0 + ii;
    tre[c][ii] = zre[idx];
    tim[c][ii] = zim[idx];
  }
  __syncthreads();
  int o = threadIdx.x & 63, ry = threadIdx.x >> 6; // 0..3
  for (int p = 0; p < 16; ++p) {
    int r = ry + 4 * p;            // 0..63
    int n = h0 * 2 + r;
    float v = (r & 1) ? tim[o][r >> 1] : tre[o][r >> 1];
    out[((size_t)(b * N_ + n)) * COUT + o] = v;
  }
}

extern "C" void kernel_launch(void* const* d_in, const int* in_sizes, int n_in,
                              void* d_out, int out_size, void* d_ws, size_t ws_size,
                              hipStream_t stream) {
  const float* x    = (const float*)d_in[0];   // (B, N, Cin)
  const float* temb = (const float*)d_in[1];   // (B, T)
  const float* wr   = (const float*)d_in[2];   // (M, Cin, Cout)
  const float* wi   = (const float*)d_in[3];
  const float* dwr  = (const float*)d_in[4];   // (M, T)
  const float* dwi  = (const float*)d_in[5];
  float* out = (float*)d_out;                  // (B, N, Cout)

  float* ws  = (float*)d_ws;
  float* tmr = ws;                         // 32784
  float* tmi = tmr + 32784;                // 32784
  float* zre = tmi + 32784;                // 8388608  (B*C, H) — reused by inverse
  float* zim = zre + 8388608;              // 8388608
  float* Xre = zim + 8388608;              // 2098176  X (b,c,k) — later Yt (b,o,k)
  float* Xim = Xre + 2098176;              // 2098176
  float* Xtr = Xim + 2098176;              // 2098176  Xt (k,b,c) — later Y (i,b,o) in-place
  float* Xti = Xtr + 2098176;              // 2098176
  // total ~96.3 MiB of workspace

  // A: t_mod
  tmod_kernel<<<dim3((B_ * M_ + 3) / 4), 256, 0, stream>>>(temb, dwr, dwi, tmr, tmi);
  // T1: pack + transpose x -> z planes
  pack_transpose<<<dim3(N_ / 64, B_), 256, 0, stream>>>(x, zre, zim);
  // B: forward FFTs
  fft_fwd<<<dim3(B_ * CIN), 512, 0, stream>>>(zre, zim, Xre, Xim);
  // T2: X (bc,k) -> Xt (k,bc)
  transpose2<<<dim3((M_ + 31) / 32, (B_ * CIN + 31) / 32, 2), 256, 0, stream>>>(
      Xre, Xim, Xtr, Xti, B_ * CIN, M_);
  // C: mix (in place over Xt)
  mix_kernel<<<dim3(M_), 256, 0, stream>>>(Xtr, Xti, wr, wi, tmr, tmi, Xtr, Xti);
  // T3: Y (i,bo) -> Yt (bo,i)  (into the dead X buffers)
  transpose2<<<dim3((B_ * COUT + 31) / 32, (M_ + 31) / 32, 2), 256, 0, stream>>>(
      Xtr, Xti, Xre, Xim, M_, B_ * COUT);
  // D: inverse FFTs (z buffers are dead, reuse)
  fft_inv<<<dim3(B_ * COUT), 512, 0, stream>>>(Xre, Xim, zre, zim);
  // T4: unpack + transpose z -> out
  unpack_transpose<<<dim3(H_ / 32, B_), 256, 0, stream>>>(zre, zim, out);
}

// Round 2
// 298.946 us; speedup vs baseline: 1.3301x; 1.3301x over previous
//
#include <hip/hip_runtime.h>
#include <math.h>

#define B_   16
#define N_   16384
#define H_   8192      // N/2
#define LOGH 13
#define CIN  64
#define COUT 64
#define T_   256
#define M_   2049

__device__ __forceinline__ unsigned br13(unsigned v) {
  return __brev(v) >> 19;   // 13-bit reversal
}

// XOR bank swizzle: bank(n) = (n ^ n>>5 ^ n>>10) & 31. Bijective per 32-block.
// Verified: bitrev scatter, stride-1/16/256/4096 patterns all <=2 lanes/bank.
__device__ __forceinline__ int SW(int n) {
  return (n & ~31) | ((n ^ (n >> 5) ^ (n >> 10)) & 31);
}

__device__ __forceinline__ void cmul(float ar, float ai, float br, float bi,
                                     float& rr, float& ri) {
  rr = ar * br - ai * bi;
  ri = ar * bi + ai * br;
}

// cos/sin of 2*pi*m/16
__device__ __constant__ float C16[16] = {
  1.f, 0.92387953251f, 0.70710678119f, 0.38268343236f, 0.f, -0.38268343236f,
  -0.70710678119f, -0.92387953251f, -1.f, -0.92387953251f, -0.70710678119f,
  -0.38268343236f, 0.f, 0.38268343236f, 0.70710678119f, 0.92387953251f};
__device__ __constant__ float S16[16] = {
  0.f, 0.38268343236f, 0.70710678119f, 0.92387953251f, 1.f, 0.92387953251f,
  0.70710678119f, 0.38268343236f, 0.f, -0.38268343236f, -0.70710678119f,
  -0.92387953251f, -1.f, -0.92387953251f, -0.70710678119f, -0.38268343236f};

// One radix-16 group = 4 radix-2 DIT substages done in registers.
// Elements: idx = hi*2^(S0+4) + j*2^S0 + lo, j=0..15; thread t: lo=t&(2^S0-1), hi=t>>S0.
template <int SIGN, int S0>
__device__ __forceinline__ void group16(float* __restrict__ sre,
                                        float* __restrict__ sim, int tid) {
  const int lo = tid & ((1 << S0) - 1);
  const int hi = tid >> S0;
  const int base = (hi << (S0 + 4)) + lo;
  int pp[16];
  float xr[16], xi[16];
#pragma unroll
  for (int j = 0; j < 16; ++j) {
    pp[j] = SW(base + (j << S0));
    xr[j] = sre[pp[j]];
    xi[j] = sim[pp[j]];
  }
  // base twiddle W = e^{SIGN*i*theta}, theta = 2*pi*lo / 2^(S0+4)
  float th = 6.283185307179586f * (float)lo / (float)(16 << S0);
  float sn, cs;
  __sincosf(th, &sn, &cs);
  float w1r = cs, w1i = (float)SIGN * sn;
  float w2r, w2i, w4r, w4i, w8r, w8i;
  cmul(w1r, w1i, w1r, w1i, w2r, w2i);
  cmul(w2r, w2i, w2r, w2i, w4r, w4i);
  cmul(w4r, w4i, w4r, w4i, w8r, w8i);
  // d=0: pairs (j, j+1), twiddle W^8
  {
#pragma unroll
    for (int j = 0; j < 16; j += 2) {
      float br, bi;
      cmul(xr[j + 1], xi[j + 1], w8r, w8i, br, bi);
      xr[j + 1] = xr[j] - br; xi[j + 1] = xi[j] - bi;
      xr[j] += br; xi[j] += bi;
    }
  }
  // d=1: pairs (j, j+2), twiddle W^4 * R16[4*jl]
  {
    float tr[2], ti[2];
    tr[0] = w4r; ti[0] = w4i;
    cmul(w4r, w4i, C16[4], (float)SIGN * S16[4], tr[1], ti[1]);
#pragma unroll
    for (int j = 0; j < 16; ++j) {
      if ((j & 2) == 0) {
        int jl = j & 1;
        float br, bi;
        cmul(xr[j + 2], xi[j + 2], tr[jl], ti[jl], br, bi);
        xr[j + 2] = xr[j] - br; xi[j + 2] = xi[j] - bi;
        xr[j] += br; xi[j] += bi;
      }
    }
  }
  // d=2: pairs (j, j+4), twiddle W^2 * R16[2*jl]
  {
    float tr[4], ti[4];
#pragma unroll
    for (int jl = 0; jl < 4; ++jl)
      cmul(w2r, w2i, C16[2 * jl], (float)SIGN * S16[2 * jl], tr[jl], ti[jl]);
#pragma unroll
    for (int j = 0; j < 16; ++j) {
      if ((j & 4) == 0) {
        int jl = j & 3;
        float br, bi;
        cmul(xr[j + 4], xi[j + 4], tr[jl], ti[jl], br, bi);
        xr[j + 4] = xr[j] - br; xi[j + 4] = xi[j] - bi;
        xr[j] += br; xi[j] += bi;
      }
    }
  }
  // d=3: pairs (j, j+8), twiddle W * R16[jl]
  {
    float tr[8], ti[8];
#pragma unroll
    for (int jl = 0; jl < 8; ++jl)
      cmul(w1r, w1i, C16[jl], (float)SIGN * S16[jl], tr[jl], ti[jl]);
#pragma unroll
    for (int j = 0; j < 8; ++j) {
      float br, bi;
      cmul(xr[j + 8], xi[j + 8], tr[j], ti[j], br, bi);
      xr[j + 8] = xr[j] - br; xi[j + 8] = xi[j] - bi;
      xr[j] += br; xi[j] += bi;
    }
  }
#pragma unroll
  for (int j = 0; j < 16; ++j) {
    sre[pp[j]] = xr[j];
    sim[pp[j]] = xi[j];
  }
}

// Final radix-2 stage (lh=12): pairs (n, n+4096), n = tid + 512*s.
// angle = SIGN*2*pi*n/8192 = theta_t + s*2*pi/16.
template <int SIGN>
__device__ __forceinline__ void stageD(float* __restrict__ sre,
                                       float* __restrict__ sim, int tid) {
  float th = 6.283185307179586f * (float)tid / 8192.0f;
  float sn, cs;
  __sincosf(th, &sn, &cs);
  float wtr = cs, wti = (float)SIGN * sn;
#pragma unroll
  for (int s = 0; s < 8; ++s) {
    float twr, twi;
    cmul(wtr, wti, C16[s], (float)SIGN * S16[s], twr, twi);
    int i0 = tid + 512 * s;
    int p0 = SW(i0), p1 = SW(i0 + 4096);
    float br, bi;
    cmul(sre[p1], sim[p1], twr, twi, br, bi);
    float ar = sre[p0], ai = sim[p0];
    sre[p0] = ar + br; sim[p0] = ai + bi;
    sre[p1] = ar - br; sim[p1] = ai - bi;
  }
}

// ---------------- Kernel A: t_mod = t_emb @ dense^T (complex) ----------------
__global__ __launch_bounds__(256) void tmod_kernel(
    const float* __restrict__ t_emb,
    const float* __restrict__ dwr, const float* __restrict__ dwi,
    float* __restrict__ tmr, float* __restrict__ tmi) {
  int wave = threadIdx.x >> 6;
  int lane = threadIdx.x & 63;
  int p = blockIdx.x * 4 + wave;
  if (p >= B_ * M_) return;
  int b = p / M_, i = p % M_;
  float ar = 0.f, ai = 0.f;
  for (int j = 0; j < 4; ++j) {
    int t = lane + 64 * j;
    float te = t_emb[b * T_ + t];
    ar += te * dwr[(size_t)i * T_ + t];
    ai += te * dwi[(size_t)i * T_ + t];
  }
  for (int off = 32; off > 0; off >>= 1) {
    ar += __shfl_down(ar, off, 64);
    ai += __shfl_down(ai, off, 64);
  }
  if (lane == 0) { tmr[b * M_ + i] = ar; tmi[b * M_ + i] = ai; }
}

// ------- Kernel T1: x (B,N,C) -> packed complex planes z (B*C, H) ------------
__global__ __launch_bounds__(256) void pack_transpose(
    const float* __restrict__ x, float* __restrict__ zre, float* __restrict__ zim) {
  __shared__ float tile[64][65];
  int b = blockIdx.y, nt = blockIdx.x;
  int n0 = nt * 64;
  int j  = threadIdx.x & 63;
  int iy = threadIdx.x >> 6;
  for (int p = 0; p < 16; ++p) {
    int i = iy + 4 * p;
    tile[i][j] = x[((size_t)(b * N_ + n0 + i)) * CIN + j];
  }
  __syncthreads();
  int ii = threadIdx.x & 31;
  int cy = threadIdx.x >> 5;
  int h0 = nt * 32;
  for (int p = 0; p < 8; ++p) {
    int c = cy + 8 * p;
    size_t o = (size_t)(b * CIN + c) * H_ + h0 + ii;
    zre[o] = tile[2 * ii][c];
    zim[o] = tile[2 * ii + 1][c];
  }
}

// ---------------- Kernel B: forward FFT (length H) + rfft split --------------
__global__ __launch_bounds__(512, 4) void fft_fwd(
    const float* __restrict__ zre, const float* __restrict__ zim,
    float* __restrict__ Xre, float* __restrict__ Xim) {
  __shared__ float sre[H_], sim[H_];
  int bc = blockIdx.x;
  int tid = threadIdx.x;
  size_t base = (size_t)bc * H_;
#pragma unroll
  for (int s = 0; s < 16; ++s) {
    int n = tid + 512 * s;
    int r = SW((int)br13(n));
    sre[r] = zre[base + n];
    sim[r] = zim[base + n];
  }
  __syncthreads();
  group16<-1, 0>(sre, sim, tid); __syncthreads();
  group16<-1, 4>(sre, sim, tid); __syncthreads();
  group16<-1, 8>(sre, sim, tid); __syncthreads();
  stageD<-1>(sre, sim, tid);     __syncthreads();
  // rfft split: X_k = E + e^{-2pi i k/N} O, then * 1/N
  const float sc = 1.0f / (float)N_;
  for (int k = tid; k < M_; k += 512) {
    int mk = (H_ - k) & (H_ - 1);
    int pk = SW(k), pm = SW(mk);
    float zr = sre[pk], zi = sim[pk];
    float mr = sre[pm], mi = -sim[pm];    // conj(Z[H-k])
    float Er = 0.5f * (zr + mr), Ei = 0.5f * (zi + mi);
    float Dr = zr - mr,          Di = zi - mi;
    float Or = 0.5f * Di,        Oi = -0.5f * Dr;  // D/(2i)
    float ang = -6.283185307179586f * (float)k / (float)N_;
    float sn, cs;
    __sincosf(ang, &sn, &cs);
    float Xr = Er + cs * Or - sn * Oi;
    float Xi = Ei + cs * Oi + sn * Or;
    Xre[(size_t)bc * M_ + k] = Xr * sc;
    Xim[(size_t)bc * M_ + k] = Xi * sc;
  }
}

// ---------------- generic 2-plane tiled transpose (R x C -> C x R) ----------
__global__ __launch_bounds__(256) void transpose2(
    const float* __restrict__ s0, const float* __restrict__ s1,
    float* __restrict__ d0, float* __restrict__ d1, int R, int C) {
  __shared__ float tile[32][33];
  const float* src = blockIdx.z ? s1 : s0;
  float* dst = blockIdx.z ? d1 : d0;
  int c0 = blockIdx.x * 32, r0 = blockIdx.y * 32;
  int tx = threadIdx.x & 31, ty = threadIdx.x >> 5;
  for (int p = 0; p < 32; p += 8) {
    int r = r0 + ty + p, c = c0 + tx;
    tile[ty + p][tx] = (r < R && c < C) ? src[(size_t)r * C + c] : 0.f;
  }
  __syncthreads();
  for (int p = 0; p < 32; p += 8) {
    int r = c0 + ty + p, c = r0 + tx;
    if (r < C && c < R) dst[(size_t)r * R + c] = tile[tx][ty + p];
  }
}

// ---------------- Kernel C: per-frequency channel mix ------------------------
// Y[i,b,o] = tmod[b,i] * sum_c X[i,b,c]*W[i,c,o]
__global__ __launch_bounds__(256) void mix_kernel(
    const float* __restrict__ Xtr, const float* __restrict__ Xti,
    const float* __restrict__ Wr_g, const float* __restrict__ Wi_g,
    const float* __restrict__ tmr, const float* __restrict__ tmi,
    float* __restrict__ Yr_g, float* __restrict__ Yi_g) {
  __shared__ float2 Wsh[4096];
  __shared__ float2 Xsh[1024];
  int i = blockIdx.x;
  int tid = threadIdx.x;
  for (int idx = tid; idx < 4096; idx += 256)
    Wsh[idx] = make_float2(Wr_g[(size_t)i * 4096 + idx], Wi_g[(size_t)i * 4096 + idx]);
  for (int idx = tid; idx < 1024; idx += 256)
    Xsh[idx] = make_float2(Xtr[(size_t)i * 1024 + idx], Xti[(size_t)i * 1024 + idx]);
  __syncthreads();
  int o = tid & 63, bq = tid >> 6;
  float ar[4] = {0.f, 0.f, 0.f, 0.f}, ai[4] = {0.f, 0.f, 0.f, 0.f};
  for (int c = 0; c < 64; ++c) {
    float2 w = Wsh[c * 64 + o];
#pragma unroll
    for (int bb = 0; bb < 4; ++bb) {
      float2 xv = Xsh[(bq + 4 * bb) * 64 + c];   // broadcast within wave
      ar[bb] += xv.x * w.x - xv.y * w.y;
      ai[bb] += xv.x * w.y + xv.y * w.x;
    }
  }
#pragma unroll
  for (int bb = 0; bb < 4; ++bb) {
    int b = bq + 4 * bb;
    float tr = tmr[b * M_ + i], ti = tmi[b * M_ + i];
    float yr = tr * ar[bb] - ti * ai[bb];
    float yi = tr * ai[bb] + ti * ar[bb];
    size_t oidx = ((size_t)i * 16 + b) * 64 + o;
    Yr_g[oidx] = yr;
    Yi_g[oidx] = yi;
  }
}

// ---------------- Kernel D: inverse packing + inverse FFT --------------------
__global__ __launch_bounds__(512, 4) void fft_inv(
    const float* __restrict__ Ytr, const float* __restrict__ Yti,
    float* __restrict__ zre, float* __restrict__ zim) {
  __shared__ float sre[H_], sim[H_];
  int bo = blockIdx.x;
  int tid = threadIdx.x;
  size_t ybase = (size_t)bo * M_;
#pragma unroll
  for (int s = 0; s < 16; ++s) {
    int k = tid + 512 * s;
    float ykr = 0.f, yki = 0.f, ymr = 0.f, ymi = 0.f;
    if (k < M_) { ykr = Ytr[ybase + k]; yki = Yti[ybase + k]; }
    int m = H_ - k;                    // 1..8192 — no wraparound (Y_H = 0)
    if (m < M_) { ymr = Ytr[ybase + m]; ymi = -Yti[ybase + m]; } // conj
    float Sr = ykr + ymr, Si = yki + ymi;
    float Dr = ykr - ymr, Di = yki - ymi;
    float ang = 6.283185307179586f * (float)k / (float)N_;
    float sn, cs;
    __sincosf(ang, &sn, &cs);
    float Zr = Sr - (cs * Di + sn * Dr);
    float Zi = Si + (cs * Dr - sn * Di);
    int r = SW((int)br13(k));
    sre[r] = Zr; sim[r] = Zi;
  }
  __syncthreads();
  group16<1, 0>(sre, sim, tid); __syncthreads();
  group16<1, 4>(sre, sim, tid); __syncthreads();
  group16<1, 8>(sre, sim, tid); __syncthreads();
  stageD<1>(sre, sim, tid);     __syncthreads();
  size_t base = (size_t)bo * H_;
#pragma unroll
  for (int s = 0; s < 16; ++s) {
    int n = tid + 512 * s;
    int p = SW(n);
    zre[base + n] = sre[p];
    zim[base + n] = sim[p];
  }
}

// ------- Kernel T4: z planes (B*Cout, H) -> out (B, N, Cout) -----------------
__global__ __launch_bounds__(256) void unpack_transpose(
    const float* __restrict__ zre, const float* __restrict__ zim,
    float* __restrict__ out) {
  __shared__ float tre[64][33], tim[64][33];
  int b = blockIdx.y, ht = blockIdx.x;
  int h0 = ht * 32;
  int ii = threadIdx.x & 31, cy = threadIdx.x >> 5;
  for (int p = 0; p < 8; ++p) {
    int c = cy + 8 * p;
    size_t idx = (size_t)(b * COUT + c) * H_ + h0 + ii;
    tre[c][ii] = zre[idx];
    tim[c][ii] = zim[idx];
  }
  __syncthreads();
  int o = threadIdx.x & 63, ry = threadIdx.x >> 6;
  for (int p = 0; p < 16; ++p) {
    int r = ry + 4 * p;
    int n = h0 * 2 + r;
    float v = (r & 1) ? tim[o][r >> 1] : tre[o][r >> 1];
    out[((size_t)(b * N_ + n)) * COUT + o] = v;
  }
}

extern "C" void kernel_launch(void* const* d_in, const int* in_sizes, int n_in,
                              void* d_out, int out_size, void* d_ws, size_t ws_size,
                              hipStream_t stream) {
  const float* x    = (const float*)d_in[0];
  const float* temb = (const float*)d_in[1];
  const float* wr   = (const float*)d_in[2];
  const float* wi   = (const float*)d_in[3];
  const float* dwr  = (const float*)d_in[4];
  const float* dwi  = (const float*)d_in[5];
  float* out = (float*)d_out;

  float* ws  = (float*)d_ws;
  float* tmr = ws;
  float* tmi = tmr + 32784;
  float* zre = tmi + 32784;                // (B*C, H) — reused by inverse
  float* zim = zre + 8388608;
  float* Xre = zim + 8388608;              // X (b,c,k) — later Yt (b,o,k)
  float* Xim = Xre + 2098176;
  float* Xtr = Xim + 2098176;              // Xt (k,b,c) — later Y (i,b,o)
  float* Xti = Xtr + 2098176;

  tmod_kernel<<<dim3((B_ * M_ + 3) / 4), 256, 0, stream>>>(temb, dwr, dwi, tmr, tmi);
  pack_transpose<<<dim3(N_ / 64, B_), 256, 0, stream>>>(x, zre, zim);
  fft_fwd<<<dim3(B_ * CIN), 512, 0, stream>>>(zre, zim, Xre, Xim);
  transpose2<<<dim3((M_ + 31) / 32, (B_ * CIN + 31) / 32, 2), 256, 0, stream>>>(
      Xre, Xim, Xtr, Xti, B_ * CIN, M_);
  mix_kernel<<<dim3(M_), 256, 0, stream>>>(Xtr, Xti, wr, wi, tmr, tmi, Xtr, Xti);
  transpose2<<<dim3((B_ * COUT + 31) / 32, (M_ + 31) / 32, 2), 256, 0, stream>>>(
      Xtr, Xti, Xre, Xim, M_, B_ * COUT);
  fft_inv<<<dim3(B_ * COUT), 512, 0, stream>>>(Xre, Xim, zre, zim);
  unpack_transpose<<<dim3(H_ / 32, B_), 256, 0, stream>>>(zre, zim, out);
}

// Round 3
// 286.763 us; speedup vs baseline: 1.3866x; 1.0425x over previous
//
#include <hip/hip_runtime.h>
#include <math.h>

#define B_   16
#define N_   16384
#define H_   8192      // N/2
#define LOGH 13
#define CIN  64
#define COUT 64
#define T_   256
#define M_   2049

__device__ __forceinline__ unsigned br13(unsigned v) {
  return __brev(v) >> 19;   // 13-bit reversal
}

// XOR bank swizzle: bank(n) = (n ^ n>>5 ^ n>>10) & 31. Bijective per 32-block.
__device__ __forceinline__ int SW(int n) {
  return (n & ~31) | ((n ^ (n >> 5) ^ (n >> 10)) & 31);
}

__device__ __forceinline__ void cmul(float ar, float ai, float br, float bi,
                                     float& rr, float& ri) {
  rr = ar * br - ai * bi;
  ri = ar * bi + ai * br;
}

// cos/sin of 2*pi*m/16
__device__ __constant__ float C16[16] = {
  1.f, 0.92387953251f, 0.70710678119f, 0.38268343236f, 0.f, -0.38268343236f,
  -0.70710678119f, -0.92387953251f, -1.f, -0.92387953251f, -0.70710678119f,
  -0.38268343236f, 0.f, 0.38268343236f, 0.70710678119f, 0.92387953251f};
__device__ __constant__ float S16[16] = {
  0.f, 0.38268343236f, 0.70710678119f, 0.92387953251f, 1.f, 0.92387953251f,
  0.70710678119f, 0.38268343236f, 0.f, -0.38268343236f, -0.70710678119f,
  -0.92387953251f, -1.f, -0.92387953251f, -0.70710678119f, -0.38268343236f};

// One radix-16 group = 4 radix-2 DIT substages done in registers.
template <int SIGN, int S0>
__device__ __forceinline__ void group16(float* __restrict__ sre,
                                        float* __restrict__ sim, int tid) {
  const int lo = tid & ((1 << S0) - 1);
  const int hi = tid >> S0;
  const int base = (hi << (S0 + 4)) + lo;
  int pp[16];
  float xr[16], xi[16];
#pragma unroll
  for (int j = 0; j < 16; ++j) {
    pp[j] = SW(base + (j << S0));
    xr[j] = sre[pp[j]];
    xi[j] = sim[pp[j]];
  }
  float th = 6.283185307179586f * (float)lo / (float)(16 << S0);
  float sn, cs;
  __sincosf(th, &sn, &cs);
  float w1r = cs, w1i = (float)SIGN * sn;
  float w2r, w2i, w4r, w4i, w8r, w8i;
  cmul(w1r, w1i, w1r, w1i, w2r, w2i);
  cmul(w2r, w2i, w2r, w2i, w4r, w4i);
  cmul(w4r, w4i, w4r, w4i, w8r, w8i);
  {
#pragma unroll
    for (int j = 0; j < 16; j += 2) {
      float br, bi;
      cmul(xr[j + 1], xi[j + 1], w8r, w8i, br, bi);
      xr[j + 1] = xr[j] - br; xi[j + 1] = xi[j] - bi;
      xr[j] += br; xi[j] += bi;
    }
  }
  {
    float tr[2], ti[2];
    tr[0] = w4r; ti[0] = w4i;
    cmul(w4r, w4i, C16[4], (float)SIGN * S16[4], tr[1], ti[1]);
#pragma unroll
    for (int j = 0; j < 16; ++j) {
      if ((j & 2) == 0) {
        int jl = j & 1;
        float br, bi;
        cmul(xr[j + 2], xi[j + 2], tr[jl], ti[jl], br, bi);
        xr[j + 2] = xr[j] - br; xi[j + 2] = xi[j] - bi;
        xr[j] += br; xi[j] += bi;
      }
    }
  }
  {
    float tr[4], ti[4];
#pragma unroll
    for (int jl = 0; jl < 4; ++jl)
      cmul(w2r, w2i, C16[2 * jl], (float)SIGN * S16[2 * jl], tr[jl], ti[jl]);
#pragma unroll
    for (int j = 0; j < 16; ++j) {
      if ((j & 4) == 0) {
        int jl = j & 3;
        float br, bi;
        cmul(xr[j + 4], xi[j + 4], tr[jl], ti[jl], br, bi);
        xr[j + 4] = xr[j] - br; xi[j + 4] = xi[j] - bi;
        xr[j] += br; xi[j] += bi;
      }
    }
  }
  {
    float tr[8], ti[8];
#pragma unroll
    for (int jl = 0; jl < 8; ++jl)
      cmul(w1r, w1i, C16[jl], (float)SIGN * S16[jl], tr[jl], ti[jl]);
#pragma unroll
    for (int j = 0; j < 8; ++j) {
      float br, bi;
      cmul(xr[j + 8], xi[j + 8], tr[j], ti[j], br, bi);
      xr[j + 8] = xr[j] - br; xi[j + 8] = xi[j] - bi;
      xr[j] += br; xi[j] += bi;
    }
  }
#pragma unroll
  for (int j = 0; j < 16; ++j) {
    sre[pp[j]] = xr[j];
    sim[pp[j]] = xi[j];
  }
}

// Final radix-2 stage (lh=12): pairs (n, n+4096).
template <int SIGN>
__device__ __forceinline__ void stageD(float* __restrict__ sre,
                                       float* __restrict__ sim, int tid) {
  float th = 6.283185307179586f * (float)tid / 8192.0f;
  float sn, cs;
  __sincosf(th, &sn, &cs);
  float wtr = cs, wti = (float)SIGN * sn;
#pragma unroll
  for (int s = 0; s < 8; ++s) {
    float twr, twi;
    cmul(wtr, wti, C16[s], (float)SIGN * S16[s], twr, twi);
    int i0 = tid + 512 * s;
    int p0 = SW(i0), p1 = SW(i0 + 4096);
    float br, bi;
    cmul(sre[p1], sim[p1], twr, twi, br, bi);
    float ar = sre[p0], ai = sim[p0];
    sre[p0] = ar + br; sim[p0] = ai + bi;
    sre[p1] = ar - br; sim[p1] = ai - bi;
  }
}

// ---------------- Kernel A: t_mod = t_emb @ dense^T (complex) ----------------
__global__ __launch_bounds__(256) void tmod_kernel(
    const float* __restrict__ t_emb,
    const float* __restrict__ dwr, const float* __restrict__ dwi,
    float* __restrict__ tmr, float* __restrict__ tmi) {
  int wave = threadIdx.x >> 6;
  int lane = threadIdx.x & 63;
  int p = blockIdx.x * 4 + wave;
  if (p >= B_ * M_) return;
  int b = p / M_, i = p % M_;
  float ar = 0.f, ai = 0.f;
  for (int j = 0; j < 4; ++j) {
    int t = lane + 64 * j;
    float te = t_emb[b * T_ + t];
    ar += te * dwr[(size_t)i * T_ + t];
    ai += te * dwi[(size_t)i * T_ + t];
  }
  for (int off = 32; off > 0; off >>= 1) {
    ar += __shfl_down(ar, off, 64);
    ai += __shfl_down(ai, off, 64);
  }
  if (lane == 0) { tmr[b * M_ + i] = ar; tmi[b * M_ + i] = ai; }
}

// ------- Kernel T1: x (B,N,C) -> packed complex planes z (B*C, H) ------------
__global__ __launch_bounds__(256) void pack_transpose(
    const float* __restrict__ x, float* __restrict__ zre, float* __restrict__ zim) {
  __shared__ float tile[64][65];
  int b = blockIdx.y, nt = blockIdx.x;
  int n0 = nt * 64;
  int j  = threadIdx.x & 63;
  int iy = threadIdx.x >> 6;
  for (int p = 0; p < 16; ++p) {
    int i = iy + 4 * p;
    tile[i][j] = x[((size_t)(b * N_ + n0 + i)) * CIN + j];
  }
  __syncthreads();
  int ii = threadIdx.x & 31;
  int cy = threadIdx.x >> 5;
  int h0 = nt * 32;
  for (int p = 0; p < 8; ++p) {
    int c = cy + 8 * p;
    size_t o = (size_t)(b * CIN + c) * H_ + h0 + ii;
    zre[o] = tile[2 * ii][c];
    zim[o] = tile[2 * ii + 1][c];
  }
}

// ---------------- Kernel B: forward FFT (length H) + rfft split --------------
__global__ __launch_bounds__(512, 4) void fft_fwd(
    const float* __restrict__ zre, const float* __restrict__ zim,
    float* __restrict__ Xre, float* __restrict__ Xim) {
  __shared__ float sre[H_], sim[H_];
  int bc = blockIdx.x;
  int tid = threadIdx.x;
  size_t base = (size_t)bc * H_;
#pragma unroll
  for (int s = 0; s < 16; ++s) {
    int n = tid + 512 * s;
    int r = SW((int)br13(n));
    sre[r] = zre[base + n];
    sim[r] = zim[base + n];
  }
  __syncthreads();
  group16<-1, 0>(sre, sim, tid); __syncthreads();
  group16<-1, 4>(sre, sim, tid); __syncthreads();
  group16<-1, 8>(sre, sim, tid); __syncthreads();
  stageD<-1>(sre, sim, tid);     __syncthreads();
  const float sc = 1.0f / (float)N_;
  for (int k = tid; k < M_; k += 512) {
    int mk = (H_ - k) & (H_ - 1);
    int pk = SW(k), pm = SW(mk);
    float zr = sre[pk], zi = sim[pk];
    float mr = sre[pm], mi = -sim[pm];
    float Er = 0.5f * (zr + mr), Ei = 0.5f * (zi + mi);
    float Dr = zr - mr,          Di = zi - mi;
    float Or = 0.5f * Di,        Oi = -0.5f * Dr;
    float ang = -6.283185307179586f * (float)k / (float)N_;
    float sn, cs;
    __sincosf(ang, &sn, &cs);
    float Xr = Er + cs * Or - sn * Oi;
    float Xi = Ei + cs * Oi + sn * Or;
    Xre[(size_t)bc * M_ + k] = Xr * sc;
    Xim[(size_t)bc * M_ + k] = Xi * sc;
  }
}

// ---------------- generic 2-plane tiled transpose (R x C -> C x R) ----------
__global__ __launch_bounds__(256) void transpose2(
    const float* __restrict__ s0, const float* __restrict__ s1,
    float* __restrict__ d0, float* __restrict__ d1, int R, int C) {
  __shared__ float tile[32][33];
  const float* src = blockIdx.z ? s1 : s0;
  float* dst = blockIdx.z ? d1 : d0;
  int c0 = blockIdx.x * 32, r0 = blockIdx.y * 32;
  int tx = threadIdx.x & 31, ty = threadIdx.x >> 5;
  for (int p = 0; p < 32; p += 8) {
    int r = r0 + ty + p, c = c0 + tx;
    tile[ty + p][tx] = (r < R && c < C) ? src[(size_t)r * C + c] : 0.f;
  }
  __syncthreads();
  for (int p = 0; p < 32; p += 8) {
    int r = c0 + ty + p, c = r0 + tx;
    if (r < C && c < R) dst[(size_t)r * R + c] = tile[tx][ty + p];
  }
}

// ---------------- Kernel C: per-frequency channel mix via MFMA (bf16x3) ------
// Y[i,b,o] = tmod[b,i] * sum_c X[i,b,c]*W[i,c,o]
// bf16 split: v = hi + lo; v*w ~= hi*H + hi*L + lo*H  (error ~2^-16 relative)
// Fragment layouts (verified, learn_hip m89/m120):
//   A (16x16x32): lane L holds A[m=L&15][k=(L>>4)*8+j], j=0..7
//   B:            lane L holds B[k=(L>>4)*8+j][n=L&15]
//   C/D:          lane L holds D[m=(L>>4)*4+r][n=L&15], r=0..3
typedef short  s8v  __attribute__((ext_vector_type(8)));
typedef float  f4v  __attribute__((ext_vector_type(4)));

__device__ __forceinline__ unsigned short f2bf_hi(float x) {
  unsigned u = __float_as_uint(x);
  unsigned r = (u + 0x7fffu + ((u >> 16) & 1u)) >> 16;   // RNE
  return (unsigned short)r;
}

// B-fragment LDS index: slab = (n>>4)*2 + (k>>5); L = (n&15) + ((k>>3)&3)*16; j = k&7
__device__ __forceinline__ int fbi(int k, int n) {
  return ((((n >> 4) * 2 + (k >> 5)) << 9) | (((n & 15) + (((k >> 3) & 3) << 4)) << 3) | (k & 7));
}
// A-fragment LDS index: slab = k>>5
__device__ __forceinline__ int fai(int k, int m) {
  return (((k >> 5) << 9) | (((m & 15) + (((k >> 3) & 3) << 4)) << 3) | (k & 7));
}

__global__ __launch_bounds__(256) void mix_mfma(
    const float* __restrict__ Xtr, const float* __restrict__ Xti,
    const float* __restrict__ Wr_g, const float* __restrict__ Wi_g,
    const float* __restrict__ tmr, const float* __restrict__ tmi,
    float* __restrict__ Yr_g, float* __restrict__ Yi_g) {
  __shared__ __align__(16) unsigned short BrH[4096], BrL[4096], BiH[4096], BiL[4096];
  __shared__ __align__(16) unsigned short ArH[1024], ArL[1024];
  __shared__ __align__(16) unsigned short AiH[1024], AiL[1024];
  __shared__ __align__(16) unsigned short AnH[1024], AnL[1024];  // -Ai
  __shared__ float tms[32];
  const int i   = blockIdx.x;
  const int tid = threadIdx.x;

  // --- stage W -> bf16 hi/lo fragments ---
  const float4* wr4 = (const float4*)(Wr_g + (size_t)i * 4096);
  const float4* wi4 = (const float4*)(Wi_g + (size_t)i * 4096);
#pragma unroll
  for (int it = 0; it < 4; ++it) {
    int f4 = it * 256 + tid;          // 0..1023
    float4 vr = wr4[f4];
    float4 vi = wi4[f4];
    int idx0 = f4 * 4;
    float er[4] = {vr.x, vr.y, vr.z, vr.w};
    float ei[4] = {vi.x, vi.y, vi.z, vi.w};
#pragma unroll
    for (int e = 0; e < 4; ++e) {
      int idx = idx0 + e;
      int k = idx >> 6, n = idx & 63;
      int a = fbi(k, n);
      unsigned short h = f2bf_hi(er[e]);
      float hf = __uint_as_float(((unsigned)h) << 16);
      BrH[a] = h; BrL[a] = f2bf_hi(er[e] - hf);
      h = f2bf_hi(ei[e]);
      hf = __uint_as_float(((unsigned)h) << 16);
      BiH[a] = h; BiL[a] = f2bf_hi(ei[e] - hf);
    }
  }
  // --- stage X -> bf16 hi/lo A-fragments (+negated imag) ---
  {
    float4 vr = ((const float4*)(Xtr + (size_t)i * 1024))[tid];
    float4 vi = ((const float4*)(Xti + (size_t)i * 1024))[tid];
    float er[4] = {vr.x, vr.y, vr.z, vr.w};
    float ei[4] = {vi.x, vi.y, vi.z, vi.w};
    int idx0 = tid * 4;
#pragma unroll
    for (int e = 0; e < 4; ++e) {
      int idx = idx0 + e;
      int m = idx >> 6, k = idx & 63;
      int a = fai(k, m);
      unsigned short h = f2bf_hi(er[e]);
      float hf = __uint_as_float(((unsigned)h) << 16);
      ArH[a] = h; ArL[a] = f2bf_hi(er[e] - hf);
      h = f2bf_hi(ei[e]);
      hf = __uint_as_float(((unsigned)h) << 16);
      unsigned short l = f2bf_hi(ei[e] - __uint_as_float(((unsigned)h) << 16));
      AiH[a] = h; AiL[a] = l;
      AnH[a] = h ^ 0x8000u; AnL[a] = l ^ 0x8000u;
    }
  }
  if (tid < 16) {
    tms[tid]      = tmr[tid * M_ + i];
    tms[16 + tid] = tmi[tid * M_ + i];
  }
  __syncthreads();

  const int w = tid >> 6, L = tid & 63;
  const s8v* pArH = (const s8v*)ArH; const s8v* pArL = (const s8v*)ArL;
  const s8v* pAiH = (const s8v*)AiH; const s8v* pAiL = (const s8v*)AiL;
  const s8v* pAnH = (const s8v*)AnH; const s8v* pAnL = (const s8v*)AnL;
  const s8v* pBrH = (const s8v*)BrH; const s8v* pBrL = (const s8v*)BrL;
  const s8v* pBiH = (const s8v*)BiH; const s8v* pBiL = (const s8v*)BiL;

  f4v cr = {0.f, 0.f, 0.f, 0.f}, ci = {0.f, 0.f, 0.f, 0.f};
#pragma unroll
  for (int s = 0; s < 2; ++s) {
    s8v arh = pArH[s * 64 + L], arl = pArL[s * 64 + L];
    s8v aih = pAiH[s * 64 + L], ail = pAiL[s * 64 + L];
    s8v anh = pAnH[s * 64 + L], anl = pAnL[s * 64 + L];
    int bo = (w * 2 + s) * 64 + L;
    s8v brh = pBrH[bo], brl = pBrL[bo];
    s8v bih = pBiH[bo], bil = pBiL[bo];
    cr = __builtin_amdgcn_mfma_f32_16x16x32_bf16(arh, brh, cr, 0, 0, 0);
    cr = __builtin_amdgcn_mfma_f32_16x16x32_bf16(arh, brl, cr, 0, 0, 0);
    cr = __builtin_amdgcn_mfma_f32_16x16x32_bf16(arl, brh, cr, 0, 0, 0);
    cr = __builtin_amdgcn_mfma_f32_16x16x32_bf16(anh, bih, cr, 0, 0, 0);
    cr = __builtin_amdgcn_mfma_f32_16x16x32_bf16(anh, bil, cr, 0, 0, 0);
    cr = __builtin_amdgcn_mfma_f32_16x16x32_bf16(anl, bih, cr, 0, 0, 0);
    ci = __builtin_amdgcn_mfma_f32_16x16x32_bf16(arh, bih, ci, 0, 0, 0);
    ci = __builtin_amdgcn_mfma_f32_16x16x32_bf16(arh, bil, ci, 0, 0, 0);
    ci = __builtin_amdgcn_mfma_f32_16x16x32_bf16(arl, bih, ci, 0, 0, 0);
    ci = __builtin_amdgcn_mfma_f32_16x16x32_bf16(aih, brh, ci, 0, 0, 0);
    ci = __builtin_amdgcn_mfma_f32_16x16x32_bf16(aih, brl, ci, 0, 0, 0);
    ci = __builtin_amdgcn_mfma_f32_16x16x32_bf16(ail, brh, ci, 0, 0, 0);
  }

  const int n = (L & 15) + 16 * w;
  const int quad = L >> 4;
#pragma unroll
  for (int r = 0; r < 4; ++r) {
    int m = quad * 4 + r;
    float tr = tms[m], ti = tms[16 + m];
    float yr = tr * cr[r] - ti * ci[r];
    float yi = tr * ci[r] + ti * cr[r];
    size_t o = (size_t)i * 1024 + m * 64 + n;
    Yr_g[o] = yr;
    Yi_g[o] = yi;
  }
}

// ---------------- Kernel D: inverse packing + inverse FFT --------------------
__global__ __launch_bounds__(512, 4) void fft_inv(
    const float* __restrict__ Ytr, const float* __restrict__ Yti,
    float* __restrict__ zre, float* __restrict__ zim) {
  __shared__ float sre[H_], sim[H_];
  int bo = blockIdx.x;
  int tid = threadIdx.x;
  size_t ybase = (size_t)bo * M_;
#pragma unroll
  for (int s = 0; s < 16; ++s) {
    int k = tid + 512 * s;
    float ykr = 0.f, yki = 0.f, ymr = 0.f, ymi = 0.f;
    if (k < M_) { ykr = Ytr[ybase + k]; yki = Yti[ybase + k]; }
    int m = H_ - k;
    if (m < M_) { ymr = Ytr[ybase + m]; ymi = -Yti[ybase + m]; }
    float Sr = ykr + ymr, Si = yki + ymi;
    float Dr = ykr - ymr, Di = yki - ymi;
    float ang = 6.283185307179586f * (float)k / (float)N_;
    float sn, cs;
    __sincosf(ang, &sn, &cs);
    float Zr = Sr - (cs * Di + sn * Dr);
    float Zi = Si + (cs * Dr - sn * Di);
    int r = SW((int)br13(k));
    sre[r] = Zr; sim[r] = Zi;
  }
  __syncthreads();
  group16<1, 0>(sre, sim, tid); __syncthreads();
  group16<1, 4>(sre, sim, tid); __syncthreads();
  group16<1, 8>(sre, sim, tid); __syncthreads();
  stageD<1>(sre, sim, tid);     __syncthreads();
  size_t base = (size_t)bo * H_;
#pragma unroll
  for (int s = 0; s < 16; ++s) {
    int n = tid + 512 * s;
    int p = SW(n);
    zre[base + n] = sre[p];
    zim[base + n] = sim[p];
  }
}

// ------- Kernel T4: z planes (B*Cout, H) -> out (B, N, Cout) -----------------
__global__ __launch_bounds__(256) void unpack_transpose(
    const float* __restrict__ zre, const float* __restrict__ zim,
    float* __restrict__ out) {
  __shared__ float tre[64][33], tim[64][33];
  int b = blockIdx.y, ht = blockIdx.x;
  int h0 = ht * 32;
  int ii = threadIdx.x & 31, cy = threadIdx.x >> 5;
  for (int p = 0; p < 8; ++p) {
    int c = cy + 8 * p;
    size_t idx = (size_t)(b * COUT + c) * H_ + h0 + ii;
    tre[c][ii] = zre[idx];
    tim[c][ii] = zim[idx];
  }
  __syncthreads();
  int o = threadIdx.x & 63, ry = threadIdx.x >> 6;
  for (int p = 0; p < 16; ++p) {
    int r = ry + 4 * p;
    int n = h0 * 2 + r;
    float v = (r & 1) ? tim[o][r >> 1] : tre[o][r >> 1];
    out[((size_t)(b * N_ + n)) * COUT + o] = v;
  }
}

extern "C" void kernel_launch(void* const* d_in, const int* in_sizes, int n_in,
                              void* d_out, int out_size, void* d_ws, size_t ws_size,
                              hipStream_t stream) {
  const float* x    = (const float*)d_in[0];
  const float* temb = (const float*)d_in[1];
  const float* wr   = (const float*)d_in[2];
  const float* wi   = (const float*)d_in[3];
  const float* dwr  = (const float*)d_in[4];
  const float* dwi  = (const float*)d_in[5];
  float* out = (float*)d_out;

  float* ws  = (float*)d_ws;
  float* tmr = ws;
  float* tmi = tmr + 32784;
  float* zre = tmi + 32784;                // (B*C, H) — reused by inverse
  float* zim = zre + 8388608;
  float* Xre = zim + 8388608;              // X (b,c,k) — later Yt (b,o,k)
  float* Xim = Xre + 2098176;
  float* Xtr = Xim + 2098176;              // Xt (k,b,c) — later Y (i,b,o)
  float* Xti = Xtr + 2098176;

  tmod_kernel<<<dim3((B_ * M_ + 3) / 4), 256, 0, stream>>>(temb, dwr, dwi, tmr, tmi);
  pack_transpose<<<dim3(N_ / 64, B_), 256, 0, stream>>>(x, zre, zim);
  fft_fwd<<<dim3(B_ * CIN), 512, 0, stream>>>(zre, zim, Xre, Xim);
  transpose2<<<dim3((M_ + 31) / 32, (B_ * CIN + 31) / 32, 2), 256, 0, stream>>>(
      Xre, Xim, Xtr, Xti, B_ * CIN, M_);
  mix_mfma<<<dim3(M_), 256, 0, stream>>>(Xtr, Xti, wr, wi, tmr, tmi, Xtr, Xti);
  transpose2<<<dim3((B_ * COUT + 31) / 32, (M_ + 31) / 32, 2), 256, 0, stream>>>(
      Xtr, Xti, Xre, Xim, M_, B_ * COUT);
  fft_inv<<<dim3(B_ * COUT), 512, 0, stream>>>(Xre, Xim, zre, zim);
  unpack_transpose<<<dim3(H_ / 32, B_), 256, 0, stream>>>(zre, zim, out);
}